// Round 11
// baseline (361.807 us; speedup 1.0000x reference)
//
#include <hip/hip_runtime.h>
#include <math.h>

#define Bb 2
#define Ss 2048
#define Dd 1024
#define Hh 16
#define SP 2052   // padded seq rows per batch (2 zero rows each side)

typedef unsigned short u16;
typedef __bf16 bf16x8 __attribute__((ext_vector_type(8)));
typedef float f32x4 __attribute__((ext_vector_type(4)));
typedef unsigned short u16x8 __attribute__((ext_vector_type(8)));
typedef unsigned short u16x4 __attribute__((ext_vector_type(4)));

__device__ __forceinline__ u16 f2bf(float f) {
    union { float f; unsigned int u; } c; c.f = f;
    unsigned int u = c.u + 0x7FFFu + ((c.u >> 16) & 1u);
    return (u16)(u >> 16);
}

// native RNE conversion: 1 VALU op on gfx950
__device__ __forceinline__ u16 f2bfn(float f) {
    __bf16 h = (__bf16)f;
    union { __bf16 h; u16 u; } c; c.h = h;
    return c.u;
}

__device__ __forceinline__ float bf2f(u16 h) {
    union { unsigned int u; float f; } c; c.u = ((unsigned int)h) << 16;
    return c.f;
}

__device__ __forceinline__ void gload16(const void* g, void* l) {
    __builtin_amdgcn_global_load_lds(
        (const __attribute__((address_space(1))) void*)g,
        (__attribute__((address_space(3))) void*)l, 16, 0, 0);
}

// ---------------------------------------------------------------------------
// FUSED prep: weights (bf16 + gate/scale folding) + input conversion into
// padded bf16 layout + mask compression. One launch replaces three.
// ---------------------------------------------------------------------------
#define PREP_WB 28676
#define PREP_IB 6156
#define PREP_MB 1024

__global__ __launch_bounds__(256) void prep_all(
    const float* __restrict__ Wq, const float* __restrict__ Wk,
    const float* __restrict__ Wv, const float* __restrict__ Wo,
    const float* __restrict__ w0, const float* __restrict__ b0,
    const float* __restrict__ w1, const float* __restrict__ b1,
    const float* __restrict__ gate,
    const float* __restrict__ q, const float* __restrict__ k, const float* __restrict__ v,
    const int* __restrict__ mask,
    u16* __restrict__ wqs, u16* __restrict__ wvb, u16* __restrict__ wob,
    u16* __restrict__ Wc0, u16* __restrict__ Wc1, float* __restrict__ bc,
    u16* __restrict__ qbf, u16* __restrict__ kbf, u16* __restrict__ vbf,
    unsigned int* __restrict__ bits, int* __restrict__ rowflags)
{
    int bid = blockIdx.x, tid = threadIdx.x;
    if (bid < PREP_WB) {
        int idx = bid * 256 + tid;
        const int NW = 1024 * 1024;
        if (idx < NW) { wqs[idx] = f2bf(Wq[idx] * 0.18033688011112042f); return; }
        idx -= NW;
        if (idx < NW) { wvb[idx] = f2bf(Wv[idx]); return; }
        idx -= NW;
        if (idx < NW) { wob[idx] = f2bf(Wo[idx]); return; }
        idx -= NW;
        if (idx < 512 * 3072) {
            int c = idx / 3072, rem = idx % 3072, t = rem >> 10, d = rem & 1023;
            float g = 1.f / (1.f + expf(-gate[c >> 6]));
            float vv = g * w0[(c * 1024 + d) * 3 + t];
            if (t == 1) vv += (1.f - g) * Wk[c * 1024 + d];
            Wc0[idx] = f2bf(vv);
            return;
        }
        idx -= 512 * 3072;
        if (idx < 512 * 5120) {
            int c = idx / 5120, rem = idx % 5120, t = rem >> 10, d = rem & 1023;
            int cg = c + 512;
            float g = 1.f / (1.f + expf(-gate[cg >> 6]));
            float vv = g * w1[(c * 1024 + d) * 5 + t];
            if (t == 2) vv += (1.f - g) * Wk[cg * 1024 + d];
            Wc1[idx] = f2bf(vv);
            return;
        }
        idx -= 512 * 5120;
        if (idx < 1024) {
            float g = 1.f / (1.f + expf(-gate[idx >> 6]));
            bc[idx] = g * (idx < 512 ? b0[idx] : b1[idx - 512]);
        }
        return;
    }
    if (bid < PREP_WB + PREP_IB) {
        int idx = (bid - PREP_WB) * 256 + tid;
        const int per = (Bb * SP * Dd) / 8;    // 525312
        int which = idx / per;
        if (which >= 3) return;
        int e = (idx - which * per) * 8;
        const float* src = which == 0 ? q : which == 1 ? k : v;
        u16* dst = which == 0 ? qbf : which == 1 ? kbf : vbf;
        int rp = e >> 10, col = e & 1023;
        int b = rp / SP, r = rp - b * SP;
        u16x8 o;
        if (r >= 2 && r < SP - 2) {
            const float* s = &src[((size_t)b * Ss + (r - 2)) * Dd + col];
            float4 lo = *(const float4*)s, hi = *(const float4*)(s + 4);
            o[0] = f2bf(lo.x); o[1] = f2bf(lo.y); o[2] = f2bf(lo.z); o[3] = f2bf(lo.w);
            o[4] = f2bf(hi.x); o[5] = f2bf(hi.y); o[6] = f2bf(hi.z); o[7] = f2bf(hi.w);
        } else {
            #pragma unroll
            for (int j = 0; j < 8; j++) o[j] = 0;
        }
        *(u16x8*)&dst[e] = o;
        return;
    }
    {
        int row = (bid - PREP_WB - PREP_IB) * 4 + (tid >> 6);
        int lane = tid & 63;
        const int* mp = mask + (size_t)row * Ss + lane * 32;
        unsigned int w = 0;
        #pragma unroll
        for (int j = 0; j < 32; j += 4) {
            int4 m4 = *(const int4*)&mp[j];
            if (m4.x != 0) w |= 1u << j;
            if (m4.y != 0) w |= 1u << (j + 1);
            if (m4.z != 0) w |= 1u << (j + 2);
            if (m4.w != 0) w |= 1u << (j + 3);
        }
        bits[(size_t)row * 64 + lane] = w;
        int anyz = __any(w != 0xFFFFFFFFu);
        if (lane == 0) rowflags[row] = anyz;
    }
}

// ---------------------------------------------------------------------------
// Generic 128x128-tile bf16 GEMM job (m97 structure). All params wave-uniform.
// vmode=1: C points at Vt and the epilogue writes the TRANSPOSED swizzled
// tile layout directly (4 consecutive kv-positions per lane = one aligned
// 8B store at Vt[tile*4096 + d*64 + ((c^(d&7))*8) + j0]), eliminating the
// separate Vp buffer + vtrans pass.
// ---------------------------------------------------------------------------
__device__ __forceinline__ void run_gemm_job(
    const u16* __restrict__ A, const u16* __restrict__ B, u16* __restrict__ C,
    int strB, int kS, int kL, int mB, int nB, int rO, int Cst, int vmode,
    u16* As, u16* Bsh, int lane, int wave, int waveM, int waveN)
{
    f32x4 acc[4][4];
    #pragma unroll
    for (int i = 0; i < 4; i++)
        #pragma unroll
        for (int j = 0; j < 4; j++) acc[i][j] = (f32x4){0.f, 0.f, 0.f, 0.f};

    for (int k0 = kS; k0 < kS + kL; k0 += 32) {
        __syncthreads();
        #pragma unroll
        for (int cc = 0; cc < 2; cc++) {
            int rbase = (wave * 2 + cc) * 16;
            int r = rbase + (lane >> 2);
            int gm = mB + r;
            int grow = (gm >> 11) * SP + (gm & 2047) + rO + (k0 >> 10);
            int csrc = (lane & 3) ^ (r & 3) ^ ((r >> 2) & 3);
            gload16(A + (size_t)grow * 1024 + (k0 & 1023) + csrc * 8, &As[rbase * 32]);
            int gn = nB + r;
            gload16(B + (size_t)gn * strB + k0 + csrc * 8, &Bsh[rbase * 32]);
        }
        __syncthreads();

        bf16x8 af[4], bfr[4];
        #pragma unroll
        for (int t = 0; t < 4; t++) {
            int mrow = waveM + t * 16 + (lane & 15);
            int xm = (mrow & 3) ^ ((mrow >> 2) & 3);
            af[t] = *(const bf16x8*)&As[mrow * 32 + (((lane >> 4) ^ xm)) * 8];
            int nrow = waveN + t * 16 + (lane & 15);
            int xn = (nrow & 3) ^ ((nrow >> 2) & 3);
            bfr[t] = *(const bf16x8*)&Bsh[nrow * 32 + (((lane >> 4) ^ xn)) * 8];
        }
        #pragma unroll
        for (int mt = 0; mt < 4; mt++)
            #pragma unroll
            for (int nt = 0; nt < 4; nt++)
                acc[mt][nt] = __builtin_amdgcn_mfma_f32_16x16x32_bf16(
                    af[mt], bfr[nt], acc[mt][nt], 0, 0, 0);
    }

    if (!vmode) {
        #pragma unroll
        for (int mt = 0; mt < 4; mt++)
            #pragma unroll
            for (int nt = 0; nt < 4; nt++)
                #pragma unroll
                for (int r = 0; r < 4; r++) {
                    int row = mB + waveM + mt * 16 + (lane >> 4) * 4 + r;
                    int gcol = nB + waveN + nt * 16 + (lane & 15);
                    C[(size_t)row * Cst + gcol] = f2bf(acc[mt][nt][r]);
                }
    } else {
        #pragma unroll
        for (int mt = 0; mt < 4; mt++)
            #pragma unroll
            for (int nt = 0; nt < 4; nt++) {
                int row0 = mB + waveM + mt * 16 + (lane >> 4) * 4;   // +r, r=0..3
                int gcol = nB + waveN + nt * 16 + (lane & 15);
                int b = row0 >> 11, s = row0 & 2047;
                int st = s >> 6, kv = s & 63;
                int cch = kv >> 3, j0 = kv & 7;                      // j0 in {0,4}
                int d = gcol & 63, h = gcol >> 6;
                u16x4 o;
                #pragma unroll
                for (int r = 0; r < 4; r++) o[r] = f2bf(acc[mt][nt][r]);
                *(u16x4*)&C[((size_t)((b * Hh + h) * 32 + st)) * 4096 +
                            d * 64 + ((cch ^ (d & 7)) * 8) + j0] = o;
            }
    }
}

// ---------------------------------------------------------------------------
// Consolidated bf16 MFMA GEMM: Q-proj, V-proj, conv0, conv1 in ONE launch.
// 768 blocks, every block does EXACTLY 2 K-units. XCD-pinned (R10 verified:
// FETCH 112->61.5MB). V-proj writes Vt tiles directly (vmode).
// ---------------------------------------------------------------------------
__global__ __launch_bounds__(256) void gemm_multi(
    const u16* __restrict__ qbf, const u16* __restrict__ kbf, const u16* __restrict__ vbf,
    const u16* __restrict__ wqs, const u16* __restrict__ wvb,
    const u16* __restrict__ Wc0, const u16* __restrict__ Wc1,
    u16* __restrict__ Qp, u16* __restrict__ Vt,
    u16* __restrict__ P0a, u16* __restrict__ P0b,
    u16* __restrict__ P1a, u16* __restrict__ P1b, u16* __restrict__ P1c)
{
    __shared__ u16 As[128 * 32];
    __shared__ u16 Bsh[128 * 32];
    int tid = threadIdx.x, lane = tid & 63, wave = tid >> 6;
    int waveM = (wave >> 1) * 64, waveN = (wave & 1) * 64;

    // XCD pin: each XCD gets a contiguous 96-job chunk. Bijective over [0,768).
    int bid = (blockIdx.x & 7) * 96 + (blockIdx.x >> 3);

    const u16 *A0, *B0; u16 *C0; int sB0, kS0, kL0, mB0, nB0, rO0, Cs0, vm0 = 0;
    const u16 *A1 = nullptr, *B1 = nullptr; u16 *C1 = nullptr;
    int sB1 = 0, kS1 = 0, kL1 = 0, mB1 = 0, nB1 = 0, rO1 = 0, Cs1 = 0, vm1 = 0;
    int njobs = 1;

    if (bid < 128) {
        int t = bid;
        A0 = kbf; B0 = Wc0; C0 = P0a; sB0 = 3072; kS0 = 0; kL0 = 2048;
        mB0 = (t >> 2) * 128; nB0 = (t & 3) * 128; rO0 = 1; Cs0 = 512;
    } else if (bid < 256) {
        int t = bid - 128;
        A0 = kbf; B0 = Wc1; C0 = P1a; sB0 = 5120; kS0 = 0; kL0 = 2048;
        mB0 = (t >> 2) * 128; nB0 = (t & 3) * 128; rO0 = 0; Cs0 = 512;
    } else if (bid < 384) {
        int t = bid - 256;
        A0 = kbf; B0 = Wc1; C0 = P1b; sB0 = 5120; kS0 = 2048; kL0 = 2048;
        mB0 = (t >> 2) * 128; nB0 = (t & 3) * 128; rO0 = 0; Cs0 = 512;
    } else if (bid < 512) {
        int t = bid - 384;
        A0 = kbf; B0 = Wc0; C0 = P0b; sB0 = 3072; kS0 = 2048; kL0 = 1024;
        mB0 = (t >> 2) * 128; nB0 = (t & 3) * 128; rO0 = 1; Cs0 = 512;
        A1 = kbf; B1 = Wc1; C1 = P1c; sB1 = 5120; kS1 = 4096; kL1 = 1024;
        mB1 = mB0; nB1 = nB0; rO1 = 0; Cs1 = 512;
        njobs = 2;
    } else {
        int i0 = (bid - 512) * 2, i1 = i0 + 1;
        if (i0 < 256) { A0 = qbf; B0 = wqs; C0 = Qp; }
        else { i0 -= 256; A0 = vbf; B0 = wvb; C0 = Vt; vm0 = 1; }
        sB0 = 1024; kS0 = 0; kL0 = 1024;
        mB0 = (i0 >> 3) * 128; nB0 = (i0 & 7) * 128; rO0 = 2; Cs0 = 1024;
        if (i1 < 256) { A1 = qbf; B1 = wqs; C1 = Qp; }
        else { i1 -= 256; A1 = vbf; B1 = wvb; C1 = Vt; vm1 = 1; }
        sB1 = 1024; kS1 = 0; kL1 = 1024;
        mB1 = (i1 >> 3) * 128; nB1 = (i1 & 7) * 128; rO1 = 2; Cs1 = 1024;
        njobs = 2;
    }

    run_gemm_job(A0, B0, C0, sB0, kS0, kL0, mB0, nB0, rO0, Cs0, vm0,
                 As, Bsh, lane, wave, waveM, waveN);
    if (njobs == 2)
        run_gemm_job(A1, B1, C1, sB1, kS1, kL1, mB1, nB1, rO1, Cs1, vm1,
                     As, Bsh, lane, wave, waveM, waveN);
}

// ---------------------------------------------------------------------------
// conv split-K reduction (+bias) -> bf16 Keff. (vtrans half removed: V-proj
// now writes Vt tiles directly in gemm_multi.)
// ---------------------------------------------------------------------------
__global__ __launch_bounds__(256) void conv_reduce(
    const u16* __restrict__ P0a, const u16* __restrict__ P0b,
    const u16* __restrict__ P1a, const u16* __restrict__ P1b, const u16* __restrict__ P1c,
    const float* __restrict__ bc, u16* __restrict__ Keff)
{
    int idx = blockIdx.x * 256 + threadIdx.x;
    int e = idx * 8;
    int r = e >> 9, c = e & 511;
    u16x8 a0 = *(const u16x8*)&P0a[e];
    u16x8 b0 = *(const u16x8*)&P0b[e];
    u16x8 a1 = *(const u16x8*)&P1a[e];
    u16x8 b1 = *(const u16x8*)&P1b[e];
    u16x8 c1 = *(const u16x8*)&P1c[e];
    float bias0[8], bias1[8];
    *(float4*)&bias0[0] = *(const float4*)&bc[c];
    *(float4*)&bias0[4] = *(const float4*)&bc[c + 4];
    *(float4*)&bias1[0] = *(const float4*)&bc[512 + c];
    *(float4*)&bias1[4] = *(const float4*)&bc[512 + c + 4];
    u16x8 o0, o1;
    #pragma unroll
    for (int j = 0; j < 8; j++) {
        o0[j] = f2bf(bf2f(a0[j]) + bf2f(b0[j]) + bias0[j]);
        o1[j] = f2bf(bf2f(a1[j]) + bf2f(b1[j]) + bf2f(c1[j]) + bias1[j]);
    }
    *(u16x8*)&Keff[(size_t)r * 1024 + c] = o0;
    *(u16x8*)&Keff[(size_t)r * 1024 + 512 + c] = o1;
}

// ---------------------------------------------------------------------------
// Out projection GEMM (fp32 out): out = AO @ wob^T + bo
// RETILED 64x128 (was 128x128): grid 8x64 = 512 blocks = 2/CU (was 1/CU,
// zero latency overlap). Waves split 1x4 over N; acc[4][2] per wave.
// ---------------------------------------------------------------------------
__global__ __launch_bounds__(256) void gemm_out(
    const u16* __restrict__ A, const u16* __restrict__ Bw,
    float* __restrict__ Cf32, const float* __restrict__ bias)
{
    __shared__ u16 As[64 * 32];
    __shared__ u16 Bs[128 * 32];
    int tid = threadIdx.x, lane = tid & 63, wave = tid >> 6;
    int waveN = wave * 32;
    int mBase = blockIdx.y * 64, nBase = blockIdx.x * 128;
    const int K = 1024;

    f32x4 acc[4][2];
    #pragma unroll
    for (int i = 0; i < 4; i++)
        #pragma unroll
        for (int j = 0; j < 2; j++) acc[i][j] = (f32x4){0.f, 0.f, 0.f, 0.f};

    for (int k0 = 0; k0 < K; k0 += 32) {
        __syncthreads();
        // A: one round (64 rows x 32 u16 = 4KB)
        {
            int r = wave * 16 + (lane >> 2);
            int gm = mBase + r;
            int grow = (gm >> 11) * SP + (gm & 2047) + 2;
            int csrc = (lane & 3) ^ (r & 3) ^ ((r >> 2) & 3);
            gload16(A + (size_t)grow * 1024 + k0 + csrc * 8, &As[(wave * 16) * 32]);
        }
        // B: two rounds (128 rows x 32 u16 = 8KB)
        #pragma unroll
        for (int cc = 0; cc < 2; cc++) {
            int rbase = (wave * 2 + cc) * 16;
            int r = rbase + (lane >> 2);
            int gn = nBase + r;
            int csrc = (lane & 3) ^ (r & 3) ^ ((r >> 2) & 3);
            gload16(Bw + (size_t)gn * K + k0 + csrc * 8, &Bs[rbase * 32]);
        }
        __syncthreads();

        bf16x8 af[4], bfr[2];
        #pragma unroll
        for (int t = 0; t < 4; t++) {
            int mrow = t * 16 + (lane & 15);
            int xm = (mrow & 3) ^ ((mrow >> 2) & 3);
            af[t] = *(const bf16x8*)&As[mrow * 32 + (((lane >> 4) ^ xm)) * 8];
        }
        #pragma unroll
        for (int t = 0; t < 2; t++) {
            int nrow = waveN + t * 16 + (lane & 15);
            int xn = (nrow & 3) ^ ((nrow >> 2) & 3);
            bfr[t] = *(const bf16x8*)&Bs[nrow * 32 + (((lane >> 4) ^ xn)) * 8];
        }
        #pragma unroll
        for (int mt = 0; mt < 4; mt++)
            #pragma unroll
            for (int nt = 0; nt < 2; nt++)
                acc[mt][nt] = __builtin_amdgcn_mfma_f32_16x16x32_bf16(
                    af[mt], bfr[nt], acc[mt][nt], 0, 0, 0);
    }

    #pragma unroll
    for (int mt = 0; mt < 4; mt++)
        #pragma unroll
        for (int nt = 0; nt < 2; nt++)
            #pragma unroll
            for (int r = 0; r < 4; r++) {
                int row = mBase + mt * 16 + (lane >> 4) * 4 + r;
                int gcol = nBase + waveN + nt * 16 + (lane & 15);
                Cf32[(size_t)row * 1024 + gcol] = acc[mt][nt][r] + bias[gcol];
            }
}

// ---------------------------------------------------------------------------
// bf16 MFMA flash attention, FIXED-MAX softmax (m == 0), QBLK=128, KVBLK=64.
// R9-verified: V staged through LDS once per block (VMEM/slot 40KB->16KB),
// XCD-pinned, 2-barrier body. Do not restructure without within-probe A/B.
// ---------------------------------------------------------------------------
__global__ __launch_bounds__(256) void flash_kernel(
    const u16* __restrict__ Qp, const u16* __restrict__ Keff, const u16* __restrict__ Vt,
    const unsigned int* __restrict__ maskbits, const int* __restrict__ rowflags,
    u16* __restrict__ AO)
{
    __shared__ u16 Qs[128 * 64];
    __shared__ u16 Ks[64 * 64];
    __shared__ u16 Vs[64 * 64];
    __shared__ u16 Ps[4][32 * 64];
    int tid = threadIdx.x, lane = tid & 63, wave = tid >> 6;

    // XCD-pinning remap (verified R4: FETCH 69.7 -> 12.4 MB)
    int bid = blockIdx.x;
    int xcd = bid & 7, slot = bid >> 3;
    int grp = xcd * 4 + (slot >> 4);
    int q0 = (slot & 15) * 128;
    int h = grp & 15, b = grp >> 4;

    #pragma unroll
    for (int cc = 0; cc < 4; cc++) {
        int rbase = (wave * 4 + cc) * 8;
        int r = rbase + (lane >> 3);
        int csrc = (lane & 7) ^ (r & 7);
        gload16(Qp + (size_t)(b * Ss + q0 + r) * Dd + h * 64 + csrc * 8, &Qs[rbase * 64]);
    }

    int anyz = 0;
    #pragma unroll
    for (int mt = 0; mt < 2; mt++)
        #pragma unroll
        for (int r = 0; r < 4; r++)
            anyz |= rowflags[b * Ss + q0 + wave * 32 + mt * 16 + (lane >> 4) * 4 + r];
    bool doMask = __any(anyz);

    float lrow[2][4];
    f32x4 oa[2][4];
    #pragma unroll
    for (int mt = 0; mt < 2; mt++) {
        #pragma unroll
        for (int r = 0; r < 4; r++) lrow[mt][r] = 0.f;
        #pragma unroll
        for (int nt = 0; nt < 4; nt++) oa[mt][nt] = (f32x4){0.f, 0.f, 0.f, 0.f};
    }

    __syncthreads();

    bf16x8 qa[2][2];
    #pragma unroll
    for (int mt = 0; mt < 2; mt++)
        #pragma unroll
        for (int ks = 0; ks < 2; ks++) {
            int mr = wave * 32 + mt * 16 + (lane & 15);
            int c = ks * 4 + (lane >> 4);
            qa[mt][ks] = *(const bf16x8*)&Qs[mr * 64 + (c ^ (mr & 7)) * 8];
        }

    const u16* vtiles = Vt + (size_t)((b * Hh + h) * 32) * 4096;

    for (int k0 = 0; k0 < Ss; k0 += 64) {
        // stage K tile (64 rows x 128B)
        #pragma unroll
        for (int cc = 0; cc < 2; cc++) {
            int rbase = (wave * 2 + cc) * 8;
            int r = rbase + (lane >> 3);
            int csrc = (lane & 7) ^ (r & 7);
            gload16(Keff + (size_t)(b * Ss + k0 + r) * Dd + h * 64 + csrc * 8, &Ks[rbase * 64]);
        }
        // stage V tile (8KB, pre-swizzled global layout -> linear copy)
        {
            const u16* vtile = vtiles + (size_t)(k0 >> 6) * 4096;
            #pragma unroll
            for (int cc = 0; cc < 2; cc++) {
                int off = (wave * 2 + cc) * 512;       // u16 units (1KB per round)
                gload16(vtile + off + lane * 8, &Vs[off]);
            }
        }
        __syncthreads();

        // S = Q @ Keff^T (base-2 logits)
        f32x4 sa[2][4];
        #pragma unroll
        for (int mt = 0; mt < 2; mt++)
            #pragma unroll
            for (int nt = 0; nt < 4; nt++) sa[mt][nt] = (f32x4){0.f, 0.f, 0.f, 0.f};
        bf16x8 kb[4][2];
        #pragma unroll
        for (int nt = 0; nt < 4; nt++)
            #pragma unroll
            for (int ks = 0; ks < 2; ks++) {
                int nr = nt * 16 + (lane & 15);
                int c = ks * 4 + (lane >> 4);
                kb[nt][ks] = *(const bf16x8*)&Ks[nr * 64 + (c ^ (nr & 7)) * 8];
            }
        #pragma unroll
        for (int mt = 0; mt < 2; mt++)
            #pragma unroll
            for (int nt = 0; nt < 4; nt++)
                #pragma unroll
                for (int ks = 0; ks < 2; ks++)
                    sa[mt][nt] = __builtin_amdgcn_mfma_f32_16x16x32_bf16(
                        qa[mt][ks], kb[nt][ks], sa[mt][nt], 0, 0, 0);

        // V B-frags from swizzled LDS
        bf16x8 vf[4][2];
        #pragma unroll
        for (int nt = 0; nt < 4; nt++)
            #pragma unroll
            for (int ks = 0; ks < 2; ks++) {
                int d = nt * 16 + (lane & 15);
                int c = ks * 4 + (lane >> 4);
                vf[nt][ks] = *(const bf16x8*)&Vs[d * 64 + ((c ^ (d & 7)) * 8)];
            }

        if (doMask) {
            #pragma unroll
            for (int mt = 0; mt < 2; mt++)
                #pragma unroll
                for (int r = 0; r < 4; r++) {
                    int qrow = q0 + wave * 32 + mt * 16 + (lane >> 4) * 4 + r;
                    const unsigned int* mb = &maskbits[((size_t)b * Ss + qrow) * 64 + (k0 >> 5)];
                    unsigned int w0m = mb[0], w1m = mb[1];
                    #pragma unroll
                    for (int nt = 0; nt < 4; nt++) {
                        int col = nt * 16 + (lane & 15);
                        unsigned int w = (col & 32) ? w1m : w0m;
                        if (!((w >> (col & 31)) & 1u)) sa[mt][nt][r] = -1.442695e9f;
                    }
                }
        }

        // fixed-max softmax: p = 2^s ; per-lane partial row-sum (no shuffles)
        #pragma unroll
        for (int mt = 0; mt < 2; mt++)
            #pragma unroll
            for (int r = 0; r < 4; r++) {
                float p0 = __builtin_amdgcn_exp2f(sa[mt][0][r]);
                float p1 = __builtin_amdgcn_exp2f(sa[mt][1][r]);
                float p2 = __builtin_amdgcn_exp2f(sa[mt][2][r]);
                float p3 = __builtin_amdgcn_exp2f(sa[mt][3][r]);
                sa[mt][0][r] = p0; sa[mt][1][r] = p1;
                sa[mt][2][r] = p2; sa[mt][3][r] = p3;
                lrow[mt][r] += (p0 + p1) + (p2 + p3);
            }

        // P (C-layout) -> bf16 -> wave-private swizzled LDS
        u16* pw = Ps[wave];
        #pragma unroll
        for (int mt = 0; mt < 2; mt++)
            #pragma unroll
            for (int nt = 0; nt < 4; nt++)
                #pragma unroll
                for (int r = 0; r < 4; r++) {
                    int row = mt * 16 + (lane >> 4) * 4 + r;
                    int col = nt * 16 + (lane & 15);
                    pw[row * 64 + (((col >> 3) ^ (row & 7))) * 8 + (col & 7)] =
                        f2bfn(sa[mt][nt][r]);
                }

        // O += P @ V
        bf16x8 pa[2][2];
        #pragma unroll
        for (int mt = 0; mt < 2; mt++)
            #pragma unroll
            for (int ks = 0; ks < 2; ks++) {
                int row = mt * 16 + (lane & 15);
                int c = ks * 4 + (lane >> 4);
                pa[mt][ks] = *(const bf16x8*)&pw[row * 64 + (c ^ (row & 7)) * 8];
            }
        #pragma unroll
        for (int mt = 0; mt < 2; mt++)
            #pragma unroll
            for (int nt = 0; nt < 4; nt++)
                #pragma unroll
                for (int ks = 0; ks < 2; ks++)
                    oa[mt][nt] = __builtin_amdgcn_mfma_f32_16x16x32_bf16(
                        pa[mt][ks], vf[nt][ks], oa[mt][nt], 0, 0, 0);

        __syncthreads();
    }

    // epilogue: one shuffle-reduce of lrow across the 16 lanes sharing rows
    #pragma unroll
    for (int mt = 0; mt < 2; mt++)
        #pragma unroll
        for (int r = 0; r < 4; r++) {
            float rs = lrow[mt][r];
            #pragma unroll
            for (int d = 1; d < 16; d <<= 1) rs += __shfl_xor(rs, d, 64);
            float inv = 1.f / rs;
            int qrow = q0 + wave * 32 + mt * 16 + (lane >> 4) * 4 + r;
            size_t rowbase = ((size_t)b * SP + 2 + qrow) * Dd + h * 64;
            #pragma unroll
            for (int nt = 0; nt < 4; nt++)
                AO[rowbase + nt * 16 + (lane & 15)] = f2bfn(oa[mt][nt][r] * inv);
        }
}

// ---------------------------------------------------------------------------
extern "C" void kernel_launch(void* const* d_in, const int* in_sizes, int n_in,
                              void* d_out, int out_size, void* d_ws, size_t ws_size,
                              hipStream_t stream)
{
    (void)in_sizes; (void)n_in; (void)out_size; (void)ws_size;
    const float* q    = (const float*)d_in[0];
    const float* k    = (const float*)d_in[1];
    const float* v    = (const float*)d_in[2];
    const int*   mask = (const int*)d_in[3];
    const float* Wq   = (const float*)d_in[4];
    const float* Wk   = (const float*)d_in[5];
    const float* Wv   = (const float*)d_in[6];
    const float* Wo   = (const float*)d_in[7];
    const float* bo   = (const float*)d_in[8];
    const float* w0   = (const float*)d_in[9];
    const float* b0   = (const float*)d_in[10];
    const float* w1   = (const float*)d_in[11];
    const float* b1   = (const float*)d_in[12];
    const float* gate = (const float*)d_in[13];
    float* out = (float*)d_out;

    char* p = (char*)d_ws;
    const size_t nPad = (size_t)Bb * SP * Dd;
    const size_t nBSD = (size_t)Bb * Ss * Dd;
    const size_t nHalf = (size_t)4096 * 512;   // one conv partial [4096][512]
    u16* qbf  = (u16*)p;            p += nPad * 2;
    u16* kbf  = (u16*)p;            p += nPad * 2;
    u16* vbf  = (u16*)p;            p += nPad * 2;  // aliased as AO after V-GEMM
    u16* Qp   = (u16*)p;            p += nBSD * 2;
    u16* Keff = (u16*)p;            p += nBSD * 2;
    u16* Vt   = (u16*)p;            p += nBSD * 2;  // swizzled V tiles (direct from gemm)
    u16* wqs  = (u16*)p;            p += (size_t)Dd * Dd * 2;
    u16* wvb  = (u16*)p;            p += (size_t)Dd * Dd * 2;
    u16* wob  = (u16*)p;            p += (size_t)Dd * Dd * 2;
    u16* Wc0  = (u16*)p;            p += (size_t)512 * 3072 * 2;
    u16* Wc1  = (u16*)p;            p += (size_t)512 * 5120 * 2;
    float* bc = (float*)p;          p += 1024 * 4;
    unsigned int* mbits = (unsigned int*)p; p += (size_t)Bb * Ss * 64 * 4;
    int* rflags = (int*)p;          p += (size_t)Bb * Ss * 4;
    u16* P1a = (u16*)p;             p += nHalf * 2;
    u16* P1b = (u16*)p;             p += nHalf * 2;
    u16* P1c = (u16*)p;             p += nHalf * 2;
    u16* P0a = (u16*)p;             p += nHalf * 2;
    u16* P0b = (u16*)p;             p += nHalf * 2;
    u16* AO = vbf;

    hipLaunchKernelGGL(prep_all, dim3(PREP_WB + PREP_IB + PREP_MB), dim3(256), 0, stream,
                       Wq, Wk, Wv, Wo, w0, b0, w1, b1, gate,
                       q, k, v, mask,
                       wqs, wvb, wob, Wc0, Wc1, bc,
                       qbf, kbf, vbf, mbits, rflags);

    // Q, V->Vt, conv0-split, conv1-split: 768 uniform-work blocks (3/CU)
    hipLaunchKernelGGL(gemm_multi, dim3(768), dim3(256), 0, stream,
                       qbf, kbf, vbf, wqs, wvb, Wc0, Wc1, Qp, Vt,
                       P0a, P0b, P1a, P1b, P1c);

    // conv split-K reduction only (vtrans eliminated)
    hipLaunchKernelGGL(conv_reduce, dim3(1024), dim3(256), 0, stream,
                       P0a, P0b, P1a, P1b, P1c, bc, Keff);

    hipLaunchKernelGGL(flash_kernel, dim3(512), dim3(256), 0, stream,
                       Qp, Keff, Vt, mbits, rflags, AO);

    hipLaunchKernelGGL(gemm_out, dim3(8, 64), dim3(256), 0, stream,
                       AO, wob, out, bo);
}

// Round 12
// 333.597 us; speedup vs baseline: 1.0846x; 1.0846x over previous
//
#include <hip/hip_runtime.h>
#include <math.h>

#define Bb 2
#define Ss 2048
#define Dd 1024
#define Hh 16
#define SP 2052   // padded seq rows per batch (2 zero rows each side)

typedef unsigned short u16;
typedef __bf16 bf16x8 __attribute__((ext_vector_type(8)));
typedef float f32x4 __attribute__((ext_vector_type(4)));
typedef unsigned short u16x8 __attribute__((ext_vector_type(8)));

__device__ __forceinline__ u16 f2bf(float f) {
    union { float f; unsigned int u; } c; c.f = f;
    unsigned int u = c.u + 0x7FFFu + ((c.u >> 16) & 1u);
    return (u16)(u >> 16);
}

// native RNE conversion: 1 VALU op on gfx950
__device__ __forceinline__ u16 f2bfn(float f) {
    __bf16 h = (__bf16)f;
    union { __bf16 h; u16 u; } c; c.h = h;
    return c.u;
}

__device__ __forceinline__ float bf2f(u16 h) {
    union { unsigned int u; float f; } c; c.u = ((unsigned int)h) << 16;
    return c.f;
}

__device__ __forceinline__ void gload16(const void* g, void* l) {
    __builtin_amdgcn_global_load_lds(
        (const __attribute__((address_space(1))) void*)g,
        (__attribute__((address_space(3))) void*)l, 16, 0, 0);
}

// ---------------------------------------------------------------------------
// FUSED prep: weights (bf16 + gate/scale folding) + input conversion into
// padded bf16 layout + mask compression. One launch replaces three.
// ---------------------------------------------------------------------------
#define PREP_WB 28676
#define PREP_IB 6156
#define PREP_MB 1024

__global__ __launch_bounds__(256) void prep_all(
    const float* __restrict__ Wq, const float* __restrict__ Wk,
    const float* __restrict__ Wv, const float* __restrict__ Wo,
    const float* __restrict__ w0, const float* __restrict__ b0,
    const float* __restrict__ w1, const float* __restrict__ b1,
    const float* __restrict__ gate,
    const float* __restrict__ q, const float* __restrict__ k, const float* __restrict__ v,
    const int* __restrict__ mask,
    u16* __restrict__ wqs, u16* __restrict__ wvb, u16* __restrict__ wob,
    u16* __restrict__ Wc0, u16* __restrict__ Wc1, float* __restrict__ bc,
    u16* __restrict__ qbf, u16* __restrict__ kbf, u16* __restrict__ vbf,
    unsigned int* __restrict__ bits, int* __restrict__ rowflags)
{
    int bid = blockIdx.x, tid = threadIdx.x;
    if (bid < PREP_WB) {
        int idx = bid * 256 + tid;
        const int NW = 1024 * 1024;
        if (idx < NW) { wqs[idx] = f2bf(Wq[idx] * 0.18033688011112042f); return; }
        idx -= NW;
        if (idx < NW) { wvb[idx] = f2bf(Wv[idx]); return; }
        idx -= NW;
        if (idx < NW) { wob[idx] = f2bf(Wo[idx]); return; }
        idx -= NW;
        if (idx < 512 * 3072) {
            int c = idx / 3072, rem = idx % 3072, t = rem >> 10, d = rem & 1023;
            float g = 1.f / (1.f + expf(-gate[c >> 6]));
            float vv = g * w0[(c * 1024 + d) * 3 + t];
            if (t == 1) vv += (1.f - g) * Wk[c * 1024 + d];
            Wc0[idx] = f2bf(vv);
            return;
        }
        idx -= 512 * 3072;
        if (idx < 512 * 5120) {
            int c = idx / 5120, rem = idx % 5120, t = rem >> 10, d = rem & 1023;
            int cg = c + 512;
            float g = 1.f / (1.f + expf(-gate[cg >> 6]));
            float vv = g * w1[(c * 1024 + d) * 5 + t];
            if (t == 2) vv += (1.f - g) * Wk[cg * 1024 + d];
            Wc1[idx] = f2bf(vv);
            return;
        }
        idx -= 512 * 5120;
        if (idx < 1024) {
            float g = 1.f / (1.f + expf(-gate[idx >> 6]));
            bc[idx] = g * (idx < 512 ? b0[idx] : b1[idx - 512]);
        }
        return;
    }
    if (bid < PREP_WB + PREP_IB) {
        int idx = (bid - PREP_WB) * 256 + tid;
        const int per = (Bb * SP * Dd) / 8;    // 525312
        int which = idx / per;
        if (which >= 3) return;
        int e = (idx - which * per) * 8;
        const float* src = which == 0 ? q : which == 1 ? k : v;
        u16* dst = which == 0 ? qbf : which == 1 ? kbf : vbf;
        int rp = e >> 10, col = e & 1023;
        int b = rp / SP, r = rp - b * SP;
        u16x8 o;
        if (r >= 2 && r < SP - 2) {
            const float* s = &src[((size_t)b * Ss + (r - 2)) * Dd + col];
            float4 lo = *(const float4*)s, hi = *(const float4*)(s + 4);
            o[0] = f2bf(lo.x); o[1] = f2bf(lo.y); o[2] = f2bf(lo.z); o[3] = f2bf(lo.w);
            o[4] = f2bf(hi.x); o[5] = f2bf(hi.y); o[6] = f2bf(hi.z); o[7] = f2bf(hi.w);
        } else {
            #pragma unroll
            for (int j = 0; j < 8; j++) o[j] = 0;
        }
        *(u16x8*)&dst[e] = o;
        return;
    }
    {
        int row = (bid - PREP_WB - PREP_IB) * 4 + (tid >> 6);
        int lane = tid & 63;
        const int* mp = mask + (size_t)row * Ss + lane * 32;
        unsigned int w = 0;
        #pragma unroll
        for (int j = 0; j < 32; j += 4) {
            int4 m4 = *(const int4*)&mp[j];
            if (m4.x != 0) w |= 1u << j;
            if (m4.y != 0) w |= 1u << (j + 1);
            if (m4.z != 0) w |= 1u << (j + 2);
            if (m4.w != 0) w |= 1u << (j + 3);
        }
        bits[(size_t)row * 64 + lane] = w;
        int anyz = __any(w != 0xFFFFFFFFu);
        if (lane == 0) rowflags[row] = anyz;
    }
}

// ---------------------------------------------------------------------------
// Generic 128x128-tile bf16 GEMM job (m97 structure). All params wave-uniform.
// R10-verified epilogue (contiguous row stores). vmode experiment REVERTED:
// it cost +40 VGPR (both epilogues co-allocated) and scattered 8B/128B-line
// stores -> gemm 81->113us (R11).
// ---------------------------------------------------------------------------
__device__ __forceinline__ void run_gemm_job(
    const u16* __restrict__ A, const u16* __restrict__ B, u16* __restrict__ C,
    int strB, int kS, int kL, int mB, int nB, int rO, int Cst,
    u16* As, u16* Bsh, int lane, int wave, int waveM, int waveN)
{
    f32x4 acc[4][4];
    #pragma unroll
    for (int i = 0; i < 4; i++)
        #pragma unroll
        for (int j = 0; j < 4; j++) acc[i][j] = (f32x4){0.f, 0.f, 0.f, 0.f};

    for (int k0 = kS; k0 < kS + kL; k0 += 32) {
        __syncthreads();
        #pragma unroll
        for (int cc = 0; cc < 2; cc++) {
            int rbase = (wave * 2 + cc) * 16;
            int r = rbase + (lane >> 2);
            int gm = mB + r;
            int grow = (gm >> 11) * SP + (gm & 2047) + rO + (k0 >> 10);
            int csrc = (lane & 3) ^ (r & 3) ^ ((r >> 2) & 3);
            gload16(A + (size_t)grow * 1024 + (k0 & 1023) + csrc * 8, &As[rbase * 32]);
            int gn = nB + r;
            gload16(B + (size_t)gn * strB + k0 + csrc * 8, &Bsh[rbase * 32]);
        }
        __syncthreads();

        bf16x8 af[4], bfr[4];
        #pragma unroll
        for (int t = 0; t < 4; t++) {
            int mrow = waveM + t * 16 + (lane & 15);
            int xm = (mrow & 3) ^ ((mrow >> 2) & 3);
            af[t] = *(const bf16x8*)&As[mrow * 32 + (((lane >> 4) ^ xm)) * 8];
            int nrow = waveN + t * 16 + (lane & 15);
            int xn = (nrow & 3) ^ ((nrow >> 2) & 3);
            bfr[t] = *(const bf16x8*)&Bsh[nrow * 32 + (((lane >> 4) ^ xn)) * 8];
        }
        #pragma unroll
        for (int mt = 0; mt < 4; mt++)
            #pragma unroll
            for (int nt = 0; nt < 4; nt++)
                acc[mt][nt] = __builtin_amdgcn_mfma_f32_16x16x32_bf16(
                    af[mt], bfr[nt], acc[mt][nt], 0, 0, 0);
    }

    #pragma unroll
    for (int mt = 0; mt < 4; mt++)
        #pragma unroll
        for (int nt = 0; nt < 4; nt++)
            #pragma unroll
            for (int r = 0; r < 4; r++) {
                int row = mB + waveM + mt * 16 + (lane >> 4) * 4 + r;
                int gcol = nB + waveN + nt * 16 + (lane & 15);
                C[(size_t)row * Cst + gcol] = f2bf(acc[mt][nt][r]);
            }
}

// ---------------------------------------------------------------------------
// Consolidated bf16 MFMA GEMM: Q-proj, V-proj, conv0, conv1 in ONE launch.
// 768 blocks, every block does EXACTLY 2 K-units. XCD-pinned (R10 verified:
// FETCH 112->61.5MB, gemm 84->81us).
// ---------------------------------------------------------------------------
__global__ __launch_bounds__(256) void gemm_multi(
    const u16* __restrict__ qbf, const u16* __restrict__ kbf, const u16* __restrict__ vbf,
    const u16* __restrict__ wqs, const u16* __restrict__ wvb,
    const u16* __restrict__ Wc0, const u16* __restrict__ Wc1,
    u16* __restrict__ Qp, u16* __restrict__ Vp,
    u16* __restrict__ P0a, u16* __restrict__ P0b,
    u16* __restrict__ P1a, u16* __restrict__ P1b, u16* __restrict__ P1c)
{
    __shared__ u16 As[128 * 32];
    __shared__ u16 Bsh[128 * 32];
    int tid = threadIdx.x, lane = tid & 63, wave = tid >> 6;
    int waveM = (wave >> 1) * 64, waveN = (wave & 1) * 64;

    // XCD pin: each XCD gets a contiguous 96-job chunk. Bijective over [0,768).
    int bid = (blockIdx.x & 7) * 96 + (blockIdx.x >> 3);

    const u16 *A0, *B0; u16 *C0; int sB0, kS0, kL0, mB0, nB0, rO0, Cs0;
    const u16 *A1 = nullptr, *B1 = nullptr; u16 *C1 = nullptr;
    int sB1 = 0, kS1 = 0, kL1 = 0, mB1 = 0, nB1 = 0, rO1 = 0, Cs1 = 0;
    int njobs = 1;

    if (bid < 128) {
        int t = bid;
        A0 = kbf; B0 = Wc0; C0 = P0a; sB0 = 3072; kS0 = 0; kL0 = 2048;
        mB0 = (t >> 2) * 128; nB0 = (t & 3) * 128; rO0 = 1; Cs0 = 512;
    } else if (bid < 256) {
        int t = bid - 128;
        A0 = kbf; B0 = Wc1; C0 = P1a; sB0 = 5120; kS0 = 0; kL0 = 2048;
        mB0 = (t >> 2) * 128; nB0 = (t & 3) * 128; rO0 = 0; Cs0 = 512;
    } else if (bid < 384) {
        int t = bid - 256;
        A0 = kbf; B0 = Wc1; C0 = P1b; sB0 = 5120; kS0 = 2048; kL0 = 2048;
        mB0 = (t >> 2) * 128; nB0 = (t & 3) * 128; rO0 = 0; Cs0 = 512;
    } else if (bid < 512) {
        int t = bid - 384;
        A0 = kbf; B0 = Wc0; C0 = P0b; sB0 = 3072; kS0 = 2048; kL0 = 1024;
        mB0 = (t >> 2) * 128; nB0 = (t & 3) * 128; rO0 = 1; Cs0 = 512;
        A1 = kbf; B1 = Wc1; C1 = P1c; sB1 = 5120; kS1 = 4096; kL1 = 1024;
        mB1 = mB0; nB1 = nB0; rO1 = 0; Cs1 = 512;
        njobs = 2;
    } else {
        int i0 = (bid - 512) * 2, i1 = i0 + 1;
        if (i0 < 256) { A0 = qbf; B0 = wqs; C0 = Qp; }
        else { i0 -= 256; A0 = vbf; B0 = wvb; C0 = Vp; }
        sB0 = 1024; kS0 = 0; kL0 = 1024;
        mB0 = (i0 >> 3) * 128; nB0 = (i0 & 7) * 128; rO0 = 2; Cs0 = 1024;
        if (i1 < 256) { A1 = qbf; B1 = wqs; C1 = Qp; }
        else { i1 -= 256; A1 = vbf; B1 = wvb; C1 = Vp; }
        sB1 = 1024; kS1 = 0; kL1 = 1024;
        mB1 = (i1 >> 3) * 128; nB1 = (i1 & 7) * 128; rO1 = 2; Cs1 = 1024;
        njobs = 2;
    }

    run_gemm_job(A0, B0, C0, sB0, kS0, kL0, mB0, nB0, rO0, Cs0,
                 As, Bsh, lane, wave, waveM, waveN);
    if (njobs == 2)
        run_gemm_job(A1, B1, C1, sB1, kS1, kL1, mB1, nB1, rO1, Cs1,
                     As, Bsh, lane, wave, waveM, waveN);
}

// ---------------------------------------------------------------------------
// FUSED: conv split-K reduction (blocks [0,1024)) + V transpose (blocks
// [1024,2048)). V transpose emits the SWIZZLED tile layout consumed by
// flash's LDS staging (R9/R10-verified): per (b,h,kv-tile) 8KB block,
//   addr = tile*4096 + d*64 + ((c ^ (d&7))*8)   [u16 units].
// ---------------------------------------------------------------------------
__global__ __launch_bounds__(256) void reduce_trans(
    const u16* __restrict__ P0a, const u16* __restrict__ P0b,
    const u16* __restrict__ P1a, const u16* __restrict__ P1b, const u16* __restrict__ P1c,
    const float* __restrict__ bc, u16* __restrict__ Keff,
    const u16* __restrict__ Vp, u16* __restrict__ Vt)
{
    __shared__ u16 t[64 * 64];
    int bid = blockIdx.x, tid = threadIdx.x;
    if (bid < 1024) {
        int idx = bid * 256 + tid;
        int e = idx * 8;
        int r = e >> 9, c = e & 511;
        u16x8 a0 = *(const u16x8*)&P0a[e];
        u16x8 b0 = *(const u16x8*)&P0b[e];
        u16x8 a1 = *(const u16x8*)&P1a[e];
        u16x8 b1 = *(const u16x8*)&P1b[e];
        u16x8 c1 = *(const u16x8*)&P1c[e];
        float bias0[8], bias1[8];
        *(float4*)&bias0[0] = *(const float4*)&bc[c];
        *(float4*)&bias0[4] = *(const float4*)&bc[c + 4];
        *(float4*)&bias1[0] = *(const float4*)&bc[512 + c];
        *(float4*)&bias1[4] = *(const float4*)&bc[512 + c + 4];
        u16x8 o0, o1;
        #pragma unroll
        for (int j = 0; j < 8; j++) {
            o0[j] = f2bf(bf2f(a0[j]) + bf2f(b0[j]) + bias0[j]);
            o1[j] = f2bf(bf2f(a1[j]) + bf2f(b1[j]) + bf2f(c1[j]) + bias1[j]);
        }
        *(u16x8*)&Keff[(size_t)r * 1024 + c] = o0;
        *(u16x8*)&Keff[(size_t)r * 1024 + 512 + c] = o1;
        return;
    }
    {
        int vb = bid - 1024;
        int st = vb & 31, h = (vb >> 5) & 15, b = vb >> 9;
        int s0 = st * 64;
        #pragma unroll
        for (int w = 0; w < 2; w++) {
            int f = tid + w * 256;
            int row = f >> 3, c = f & 7;
            int p = c ^ (row & 7);
            u16x8 vv = *(const u16x8*)&Vp[(size_t)(b * Ss + s0 + row) * Dd + h * 64 + c * 8];
            *(u16x8*)&t[row * 64 + p * 8] = vv;
        }
        __syncthreads();
        // gather transposed d-major data, write swizzled tile layout
        size_t tbase = (size_t)((b * Hh + h) * 32 + st) * 4096;
        #pragma unroll
        for (int w = 0; w < 2; w++) {
            int f = tid + w * 256;
            int d = f >> 3, c = f & 7;       // c = kv-chunk (8 elems)
            int s8 = c * 8;
            u16x8 vv;
            #pragma unroll
            for (int j = 0; j < 8; j++) {
                int s = s8 + j;
                vv[j] = t[s * 64 + (((d >> 3) ^ (s & 7))) * 8 + (d & 7)];
            }
            *(u16x8*)&Vt[tbase + (size_t)d * 64 + ((c ^ (d & 7)) * 8)] = vv;
        }
    }
}

// ---------------------------------------------------------------------------
// Out projection GEMM (fp32 out): out = AO @ wob^T + bo
// 64x128 tiles -> 512 blocks = 2/CU (R11: ~neutral-to-positive, kept).
// ---------------------------------------------------------------------------
__global__ __launch_bounds__(256) void gemm_out(
    const u16* __restrict__ A, const u16* __restrict__ Bw,
    float* __restrict__ Cf32, const float* __restrict__ bias)
{
    __shared__ u16 As[64 * 32];
    __shared__ u16 Bs[128 * 32];
    int tid = threadIdx.x, lane = tid & 63, wave = tid >> 6;
    int waveN = wave * 32;
    int mBase = blockIdx.y * 64, nBase = blockIdx.x * 128;
    const int K = 1024;

    f32x4 acc[4][2];
    #pragma unroll
    for (int i = 0; i < 4; i++)
        #pragma unroll
        for (int j = 0; j < 2; j++) acc[i][j] = (f32x4){0.f, 0.f, 0.f, 0.f};

    for (int k0 = 0; k0 < K; k0 += 32) {
        __syncthreads();
        // A: one round (64 rows x 32 u16 = 4KB)
        {
            int r = wave * 16 + (lane >> 2);
            int gm = mBase + r;
            int grow = (gm >> 11) * SP + (gm & 2047) + 2;
            int csrc = (lane & 3) ^ (r & 3) ^ ((r >> 2) & 3);
            gload16(A + (size_t)grow * 1024 + k0 + csrc * 8, &As[(wave * 16) * 32]);
        }
        // B: two rounds (128 rows x 32 u16 = 8KB)
        #pragma unroll
        for (int cc = 0; cc < 2; cc++) {
            int rbase = (wave * 2 + cc) * 16;
            int r = rbase + (lane >> 2);
            int gn = nBase + r;
            int csrc = (lane & 3) ^ (r & 3) ^ ((r >> 2) & 3);
            gload16(Bw + (size_t)gn * K + k0 + csrc * 8, &Bs[rbase * 32]);
        }
        __syncthreads();

        bf16x8 af[4], bfr[2];
        #pragma unroll
        for (int t = 0; t < 4; t++) {
            int mrow = t * 16 + (lane & 15);
            int xm = (mrow & 3) ^ ((mrow >> 2) & 3);
            af[t] = *(const bf16x8*)&As[mrow * 32 + (((lane >> 4) ^ xm)) * 8];
        }
        #pragma unroll
        for (int t = 0; t < 2; t++) {
            int nrow = waveN + t * 16 + (lane & 15);
            int xn = (nrow & 3) ^ ((nrow >> 2) & 3);
            bfr[t] = *(const bf16x8*)&Bs[nrow * 32 + (((lane >> 4) ^ xn)) * 8];
        }
        #pragma unroll
        for (int mt = 0; mt < 4; mt++)
            #pragma unroll
            for (int nt = 0; nt < 2; nt++)
                acc[mt][nt] = __builtin_amdgcn_mfma_f32_16x16x32_bf16(
                    af[mt], bfr[nt], acc[mt][nt], 0, 0, 0);
    }

    #pragma unroll
    for (int mt = 0; mt < 4; mt++)
        #pragma unroll
        for (int nt = 0; nt < 2; nt++)
            #pragma unroll
            for (int r = 0; r < 4; r++) {
                int row = mBase + mt * 16 + (lane >> 4) * 4 + r;
                int gcol = nBase + waveN + nt * 16 + (lane & 15);
                Cf32[(size_t)row * 1024 + gcol] = acc[mt][nt][r] + bias[gcol];
            }
}

// ---------------------------------------------------------------------------
// bf16 MFMA flash attention, FIXED-MAX softmax (m == 0), QBLK=128, KVBLK=64.
// R9-verified: V staged through LDS once per block (VMEM/slot 40KB->16KB),
// XCD-pinned, 2-barrier body. Do not restructure without within-probe A/B.
// ---------------------------------------------------------------------------
__global__ __launch_bounds__(256) void flash_kernel(
    const u16* __restrict__ Qp, const u16* __restrict__ Keff, const u16* __restrict__ Vt,
    const unsigned int* __restrict__ maskbits, const int* __restrict__ rowflags,
    u16* __restrict__ AO)
{
    __shared__ u16 Qs[128 * 64];
    __shared__ u16 Ks[64 * 64];
    __shared__ u16 Vs[64 * 64];
    __shared__ u16 Ps[4][32 * 64];
    int tid = threadIdx.x, lane = tid & 63, wave = tid >> 6;

    // XCD-pinning remap (verified R4: FETCH 69.7 -> 12.4 MB)
    int bid = blockIdx.x;
    int xcd = bid & 7, slot = bid >> 3;
    int grp = xcd * 4 + (slot >> 4);
    int q0 = (slot & 15) * 128;
    int h = grp & 15, b = grp >> 4;

    #pragma unroll
    for (int cc = 0; cc < 4; cc++) {
        int rbase = (wave * 4 + cc) * 8;
        int r = rbase + (lane >> 3);
        int csrc = (lane & 7) ^ (r & 7);
        gload16(Qp + (size_t)(b * Ss + q0 + r) * Dd + h * 64 + csrc * 8, &Qs[rbase * 64]);
    }

    int anyz = 0;
    #pragma unroll
    for (int mt = 0; mt < 2; mt++)
        #pragma unroll
        for (int r = 0; r < 4; r++)
            anyz |= rowflags[b * Ss + q0 + wave * 32 + mt * 16 + (lane >> 4) * 4 + r];
    bool doMask = __any(anyz);

    float lrow[2][4];
    f32x4 oa[2][4];
    #pragma unroll
    for (int mt = 0; mt < 2; mt++) {
        #pragma unroll
        for (int r = 0; r < 4; r++) lrow[mt][r] = 0.f;
        #pragma unroll
        for (int nt = 0; nt < 4; nt++) oa[mt][nt] = (f32x4){0.f, 0.f, 0.f, 0.f};
    }

    __syncthreads();

    bf16x8 qa[2][2];
    #pragma unroll
    for (int mt = 0; mt < 2; mt++)
        #pragma unroll
        for (int ks = 0; ks < 2; ks++) {
            int mr = wave * 32 + mt * 16 + (lane & 15);
            int c = ks * 4 + (lane >> 4);
            qa[mt][ks] = *(const bf16x8*)&Qs[mr * 64 + (c ^ (mr & 7)) * 8];
        }

    const u16* vtiles = Vt + (size_t)((b * Hh + h) * 32) * 4096;

    for (int k0 = 0; k0 < Ss; k0 += 64) {
        // stage K tile (64 rows x 128B)
        #pragma unroll
        for (int cc = 0; cc < 2; cc++) {
            int rbase = (wave * 2 + cc) * 8;
            int r = rbase + (lane >> 3);
            int csrc = (lane & 7) ^ (r & 7);
            gload16(Keff + (size_t)(b * Ss + k0 + r) * Dd + h * 64 + csrc * 8, &Ks[rbase * 64]);
        }
        // stage V tile (8KB, pre-swizzled global layout -> linear copy)
        {
            const u16* vtile = vtiles + (size_t)(k0 >> 6) * 4096;
            #pragma unroll
            for (int cc = 0; cc < 2; cc++) {
                int off = (wave * 2 + cc) * 512;       // u16 units (1KB per round)
                gload16(vtile + off + lane * 8, &Vs[off]);
            }
        }
        __syncthreads();

        // S = Q @ Keff^T (base-2 logits)
        f32x4 sa[2][4];
        #pragma unroll
        for (int mt = 0; mt < 2; mt++)
            #pragma unroll
            for (int nt = 0; nt < 4; nt++) sa[mt][nt] = (f32x4){0.f, 0.f, 0.f, 0.f};
        bf16x8 kb[4][2];
        #pragma unroll
        for (int nt = 0; nt < 4; nt++)
            #pragma unroll
            for (int ks = 0; ks < 2; ks++) {
                int nr = nt * 16 + (lane & 15);
                int c = ks * 4 + (lane >> 4);
                kb[nt][ks] = *(const bf16x8*)&Ks[nr * 64 + (c ^ (nr & 7)) * 8];
            }
        #pragma unroll
        for (int mt = 0; mt < 2; mt++)
            #pragma unroll
            for (int nt = 0; nt < 4; nt++)
                #pragma unroll
                for (int ks = 0; ks < 2; ks++)
                    sa[mt][nt] = __builtin_amdgcn_mfma_f32_16x16x32_bf16(
                        qa[mt][ks], kb[nt][ks], sa[mt][nt], 0, 0, 0);

        // V B-frags from swizzled LDS
        bf16x8 vf[4][2];
        #pragma unroll
        for (int nt = 0; nt < 4; nt++)
            #pragma unroll
            for (int ks = 0; ks < 2; ks++) {
                int d = nt * 16 + (lane & 15);
                int c = ks * 4 + (lane >> 4);
                vf[nt][ks] = *(const bf16x8*)&Vs[d * 64 + ((c ^ (d & 7)) * 8)];
            }

        if (doMask) {
            #pragma unroll
            for (int mt = 0; mt < 2; mt++)
                #pragma unroll
                for (int r = 0; r < 4; r++) {
                    int qrow = q0 + wave * 32 + mt * 16 + (lane >> 4) * 4 + r;
                    const unsigned int* mb = &maskbits[((size_t)b * Ss + qrow) * 64 + (k0 >> 5)];
                    unsigned int w0m = mb[0], w1m = mb[1];
                    #pragma unroll
                    for (int nt = 0; nt < 4; nt++) {
                        int col = nt * 16 + (lane & 15);
                        unsigned int w = (col & 32) ? w1m : w0m;
                        if (!((w >> (col & 31)) & 1u)) sa[mt][nt][r] = -1.442695e9f;
                    }
                }
        }

        // fixed-max softmax: p = 2^s ; per-lane partial row-sum (no shuffles)
        #pragma unroll
        for (int mt = 0; mt < 2; mt++)
            #pragma unroll
            for (int r = 0; r < 4; r++) {
                float p0 = __builtin_amdgcn_exp2f(sa[mt][0][r]);
                float p1 = __builtin_amdgcn_exp2f(sa[mt][1][r]);
                float p2 = __builtin_amdgcn_exp2f(sa[mt][2][r]);
                float p3 = __builtin_amdgcn_exp2f(sa[mt][3][r]);
                sa[mt][0][r] = p0; sa[mt][1][r] = p1;
                sa[mt][2][r] = p2; sa[mt][3][r] = p3;
                lrow[mt][r] += (p0 + p1) + (p2 + p3);
            }

        // P (C-layout) -> bf16 -> wave-private swizzled LDS
        u16* pw = Ps[wave];
        #pragma unroll
        for (int mt = 0; mt < 2; mt++)
            #pragma unroll
            for (int nt = 0; nt < 4; nt++)
                #pragma unroll
                for (int r = 0; r < 4; r++) {
                    int row = mt * 16 + (lane >> 4) * 4 + r;
                    int col = nt * 16 + (lane & 15);
                    pw[row * 64 + (((col >> 3) ^ (row & 7))) * 8 + (col & 7)] =
                        f2bfn(sa[mt][nt][r]);
                }

        // O += P @ V
        bf16x8 pa[2][2];
        #pragma unroll
        for (int mt = 0; mt < 2; mt++)
            #pragma unroll
            for (int ks = 0; ks < 2; ks++) {
                int row = mt * 16 + (lane & 15);
                int c = ks * 4 + (lane >> 4);
                pa[mt][ks] = *(const bf16x8*)&pw[row * 64 + (c ^ (row & 7)) * 8];
            }
        #pragma unroll
        for (int mt = 0; mt < 2; mt++)
            #pragma unroll
            for (int nt = 0; nt < 4; nt++)
                #pragma unroll
                for (int ks = 0; ks < 2; ks++)
                    oa[mt][nt] = __builtin_amdgcn_mfma_f32_16x16x32_bf16(
                        pa[mt][ks], vf[nt][ks], oa[mt][nt], 0, 0, 0);

        __syncthreads();
    }

    // epilogue: one shuffle-reduce of lrow across the 16 lanes sharing rows
    #pragma unroll
    for (int mt = 0; mt < 2; mt++)
        #pragma unroll
        for (int r = 0; r < 4; r++) {
            float rs = lrow[mt][r];
            #pragma unroll
            for (int d = 1; d < 16; d <<= 1) rs += __shfl_xor(rs, d, 64);
            float inv = 1.f / rs;
            int qrow = q0 + wave * 32 + mt * 16 + (lane >> 4) * 4 + r;
            size_t rowbase = ((size_t)b * SP + 2 + qrow) * Dd + h * 64;
            #pragma unroll
            for (int nt = 0; nt < 4; nt++)
                AO[rowbase + nt * 16 + (lane & 15)] = f2bfn(oa[mt][nt][r] * inv);
        }
}

// ---------------------------------------------------------------------------
extern "C" void kernel_launch(void* const* d_in, const int* in_sizes, int n_in,
                              void* d_out, int out_size, void* d_ws, size_t ws_size,
                              hipStream_t stream)
{
    (void)in_sizes; (void)n_in; (void)out_size; (void)ws_size;
    const float* q    = (const float*)d_in[0];
    const float* k    = (const float*)d_in[1];
    const float* v    = (const float*)d_in[2];
    const int*   mask = (const int*)d_in[3];
    const float* Wq   = (const float*)d_in[4];
    const float* Wk   = (const float*)d_in[5];
    const float* Wv   = (const float*)d_in[6];
    const float* Wo   = (const float*)d_in[7];
    const float* bo   = (const float*)d_in[8];
    const float* w0   = (const float*)d_in[9];
    const float* b0   = (const float*)d_in[10];
    const float* w1   = (const float*)d_in[11];
    const float* b1   = (const float*)d_in[12];
    const float* gate = (const float*)d_in[13];
    float* out = (float*)d_out;

    char* p = (char*)d_ws;
    const size_t nPad = (size_t)Bb * SP * Dd;
    const size_t nBSD = (size_t)Bb * Ss * Dd;
    const size_t nHalf = (size_t)4096 * 512;   // one conv partial [4096][512]
    u16* qbf  = (u16*)p;            p += nPad * 2;
    u16* kbf  = (u16*)p;            p += nPad * 2;
    u16* vbf  = (u16*)p;            p += nPad * 2;  // aliased as AO after V-GEMM
    u16* Qp   = (u16*)p;            p += nBSD * 2;
    u16* Keff = (u16*)p;            p += nBSD * 2;
    u16* Vp   = (u16*)p;            p += nBSD * 2;
    u16* Vt   = (u16*)p;            p += nBSD * 2;  // swizzled V tiles
    u16* wqs  = (u16*)p;            p += (size_t)Dd * Dd * 2;
    u16* wvb  = (u16*)p;            p += (size_t)Dd * Dd * 2;
    u16* wob  = (u16*)p;            p += (size_t)Dd * Dd * 2;
    u16* Wc0  = (u16*)p;            p += (size_t)512 * 3072 * 2;
    u16* Wc1  = (u16*)p;            p += (size_t)512 * 5120 * 2;
    float* bc = (float*)p;          p += 1024 * 4;
    unsigned int* mbits = (unsigned int*)p; p += (size_t)Bb * Ss * 64 * 4;
    int* rflags = (int*)p;          p += (size_t)Bb * Ss * 4;
    u16* P1a = (u16*)p;             p += nHalf * 2;
    u16* P1b = (u16*)p;             p += nHalf * 2;
    u16* P1c = (u16*)p;             p += nHalf * 2;
    u16* P0a = (u16*)p;             p += nHalf * 2;
    u16* P0b = (u16*)p;             p += nHalf * 2;
    u16* AO = vbf;

    hipLaunchKernelGGL(prep_all, dim3(PREP_WB + PREP_IB + PREP_MB), dim3(256), 0, stream,
                       Wq, Wk, Wv, Wo, w0, b0, w1, b1, gate,
                       q, k, v, mask,
                       wqs, wvb, wob, Wc0, Wc1, bc,
                       qbf, kbf, vbf, mbits, rflags);

    // Q, V, conv0-split, conv1-split: 768 uniform-work blocks (3/CU)
    hipLaunchKernelGGL(gemm_multi, dim3(768), dim3(256), 0, stream,
                       qbf, kbf, vbf, wqs, wvb, Wc0, Wc1, Qp, Vp,
                       P0a, P0b, P1a, P1b, P1c);

    // conv_reduce (1024 blocks) + vtrans->swizzled-tiles (1024 blocks) fused
    hipLaunchKernelGGL(reduce_trans, dim3(2048), dim3(256), 0, stream,
                       P0a, P0b, P1a, P1b, P1c, bc, Keff, Vp, Vt);

    hipLaunchKernelGGL(flash_kernel, dim3(512), dim3(256), 0, stream,
                       Qp, Keff, Vt, mbits, rflags, AO);

    hipLaunchKernelGGL(gemm_out, dim3(8, 64), dim3(256), 0, stream,
                       AO, wob, out, bo);
}